// Round 4
// baseline (122.538 us; speedup 1.0000x reference)
//
#include <hip/hip_runtime.h>

#define N_SAMP 1024
#define XD     128
#define HID    256
#define KHALF  128

// ---------------------------------------------------------------------------
// Workspace layout (float indices):
//   [0, 1024)            S       per-i sum of exp(T1[i,j] - b2) over j
//   [1024]               T0sum   sum over i of T1[i,i]  (diagonal, sans b2)
//   [2048, 2048+256K)    xpbT    (x @ W1x + b1)^T   [HID][N]  (k-major)
//   [next 256K)          ypT     (y @ W1y)^T        [HID][N]  (k-major)
//   [2048+512K, +2M)     T1part  [2][N][N] split-K partial T1 tiles
// T0sum zeroed by gemm_xy; S is written directly (no init needed).
// ---------------------------------------------------------------------------

// Kernel 1: the two small GEMMs, writing TRANSPOSED outputs. Thread k owns
// hidden unit k for 4 consecutive rows -> in k-major layout those 4 results
// are contiguous: one float4 store per array. Also zeroes T0sum.
__global__ __launch_bounds__(256) void gemm_xy(
    const float* __restrict__ x, const float* __restrict__ y,
    const float* __restrict__ W1, const float* __restrict__ b1,
    float* __restrict__ xpbT, float* __restrict__ ypT,
    float* __restrict__ T0sum)
{
    const int k  = threadIdx.x;        // hidden unit 0..255
    const int r0 = blockIdx.x * 4;     // 4 rows per block

    if (blockIdx.x == 0 && threadIdx.x == 0) T0sum[0] = 0.f;

    float ax0 = 0.f, ax1 = 0.f, ax2 = 0.f, ax3 = 0.f;
    float ay0 = 0.f, ay1 = 0.f, ay2 = 0.f, ay3 = 0.f;

    #pragma unroll 4
    for (int d = 0; d < XD; ++d) {
        const float wx = W1[d * HID + k];            // coalesced over k
        const float wy = W1[(XD + d) * HID + k];
        ax0 = fmaf(x[(r0 + 0) * XD + d], wx, ax0);   // uniform -> s_load
        ax1 = fmaf(x[(r0 + 1) * XD + d], wx, ax1);
        ax2 = fmaf(x[(r0 + 2) * XD + d], wx, ax2);
        ax3 = fmaf(x[(r0 + 3) * XD + d], wx, ax3);
        ay0 = fmaf(y[(r0 + 0) * XD + d], wy, ay0);
        ay1 = fmaf(y[(r0 + 1) * XD + d], wy, ay1);
        ay2 = fmaf(y[(r0 + 2) * XD + d], wy, ay2);
        ay3 = fmaf(y[(r0 + 3) * XD + d], wy, ay3);
    }

    const float bk = b1[k];
    float4 xs = make_float4(ax0 + bk, ax1 + bk, ax2 + bk, ax3 + bk);
    float4 ys = make_float4(ay0, ay1, ay2, ay3);
    *(float4*)&xpbT[k * N_SAMP + r0] = xs;   // 16B-aligned (r0 % 4 == 0)
    *(float4*)&ypT [k * N_SAMP + r0] = ys;
}

// Kernel 2: split-K pairwise relu-dot partials.
// Round-3 post-mortem: total work is fixed, so accs/thread and waves/SIMD
// trade off hard (16 accs -> 1 wave/SIMD -> stall-bound at VALUBusy 34%).
// Split-K=2 breaks the tradeoff: 16 accs/thread AND 2 waves/SIMD, and the
// k-loop reads ONLY LDS (both panels staged; 64 KB/block -> 2 blocks/CU).
// ds_read addresses are base + compile-time immediate (row stride 256 B,
// kk*256 < 32K fits the 16-bit offset) -> zero address VALU in the loop.
__global__ __launch_bounds__(256) void pair_partial(
    const float* __restrict__ ypT, const float* __restrict__ xpbT,
    const float* __restrict__ W2, float* __restrict__ T1part)
{
    __shared__ float xs[KHALF][64];    // [kk][j] 32 KB
    __shared__ float ys[KHALF][64];    // [kk][i] 32 KB

    const int tid = threadIdx.x;
    const int tj  = tid & 15;
    const int ti  = tid >> 4;
    const int jb  = blockIdx.x * 64;
    const int ib  = blockIdx.y * 64;
    const int kof = blockIdx.z * KHALF;     // 0 or 128

    // Stage both panels: 2048 float4 each, 8 per thread per panel.
    // 16 consecutive lanes cover one 256 B row segment -> coalesced global
    // reads, contiguous conflict-free LDS writes.
    #pragma unroll
    for (int s = 0; s < 8; ++s) {
        const int f  = s * 256 + tid;
        const int kk = f >> 4;              // 16 float4 per 64-float row
        const int q  = (f & 15) * 4;
        *(float4*)&xs[kk][q] = *(const float4*)&xpbT[(kof + kk) * N_SAMP + jb + q];
        *(float4*)&ys[kk][q] = *(const float4*)&ypT [(kof + kk) * N_SAMP + ib + q];
    }
    __syncthreads();

    float acc[4][4];
    #pragma unroll
    for (int a = 0; a < 4; ++a)
        #pragma unroll
        for (int b = 0; b < 4; ++b) acc[a][b] = 0.f;

    const int tj4 = tj * 4, ti4 = ti * 4;

    #pragma unroll 8
    for (int kk = 0; kk < KHALF; ++kk) {
        const float4 xv = *(const float4*)&xs[kk][tj4];  // 16 addrs, 2-way (free)
        const float4 yv = *(const float4*)&ys[kk][ti4];  // 4 addrs, broadcast
        const float  w  = W2[kof + kk];                  // uniform -> s_load
        const float xa[4] = {xv.x, xv.y, xv.z, xv.w};
        const float ya[4] = {yv.x, yv.y, yv.z, yv.w};
        #pragma unroll
        for (int a = 0; a < 4; ++a)
            #pragma unroll
            for (int b = 0; b < 4; ++b)
                acc[a][b] = fmaf(fmaxf(ya[a] + xa[b], 0.f), w, acc[a][b]);
    }

    // Store partial tile: per a, 16 lanes write 256 B contiguous.
    float* dst = T1part + ((size_t)blockIdx.z << 20);    // 1M floats per half
    #pragma unroll
    for (int a = 0; a < 4; ++a) {
        float4 v = make_float4(acc[a][0], acc[a][1], acc[a][2], acc[a][3]);
        *(float4*)&dst[(ib + ti4 + a) * N_SAMP + jb + tj4] = v;
    }
}

// Kernel 3: one block per row i. Sum the two k-half partials, extract the
// diagonal (compile-time element select; branch is block-uniform), exp,
// block-reduce, write S[i] directly. |T1| ~ O(1): exp without max-shift
// is safe in f32.
__global__ __launch_bounds__(256) void row_lse(
    const float* __restrict__ T1part,
    float* __restrict__ S, float* __restrict__ T0sum)
{
    __shared__ float red[4];
    const int i   = blockIdx.x;
    const int tid = threadIdx.x;

    const float4 a = *(const float4*)&T1part[(size_t)i * N_SAMP + tid * 4];
    const float4 b = *(const float4*)&T1part[(1u << 20) + (size_t)i * N_SAMP + tid * 4];
    const float t0 = a.x + b.x, t1 = a.y + b.y, t2 = a.z + b.z, t3 = a.w + b.w;

    if (tid == (i >> 2)) {               // this thread holds j == i
        float d;
        if      ((i & 3) == 0) d = t0;
        else if ((i & 3) == 1) d = t1;
        else if ((i & 3) == 2) d = t2;
        else                   d = t3;
        atomicAdd(T0sum, d);             // 1024 atomics total
    }

    float e = __expf(t0) + __expf(t1) + __expf(t2) + __expf(t3);
    #pragma unroll
    for (int off = 32; off; off >>= 1) e += __shfl_xor(e, off, 64);
    if ((tid & 63) == 0) red[tid >> 6] = e;
    __syncthreads();
    if (tid == 0) S[i] = red[0] + red[1] + red[2] + red[3];
}

// Kernel 4: lse[i] = log(S[i]); combine means. Single block.
__global__ __launch_bounds__(256) void finalize(
    const float* __restrict__ S, const float* __restrict__ T0sum,
    const float* __restrict__ b2, float* __restrict__ out)
{
    __shared__ float red[4];
    const int tid = threadIdx.x;

    float ls = 0.f;
    for (int i = tid; i < N_SAMP; i += 256) ls += logf(S[i]);
    #pragma unroll
    for (int off = 32; off; off >>= 1) ls += __shfl_xor(ls, off, 64);
    if ((tid & 63) == 0) red[tid >> 6] = ls;
    __syncthreads();

    if (tid == 0) {
        const float lse_sum = red[0] + red[1] + red[2] + red[3];
        const float t0_mean  = T0sum[0] / (float)N_SAMP + b2[0];
        const float lse_mean = lse_sum / (float)N_SAMP + b2[0] - logf((float)N_SAMP);
        out[0] = t0_mean - lse_mean;
    }
}

extern "C" void kernel_launch(void* const* d_in, const int* in_sizes, int n_in,
                              void* d_out, int out_size, void* d_ws, size_t ws_size,
                              hipStream_t stream)
{
    const float* x  = (const float*)d_in[0];
    const float* y  = (const float*)d_in[1];
    const float* W1 = (const float*)d_in[2];
    const float* b1 = (const float*)d_in[3];
    const float* W2 = (const float*)d_in[4];
    const float* b2 = (const float*)d_in[5];

    float* ws     = (float*)d_ws;
    float* S      = ws;                          // 1024 floats
    float* T0s    = ws + 1024;                   // 1 float
    float* xpbT   = ws + 2048;                   // [HID][N]
    float* ypT    = ws + 2048 + HID * N_SAMP;    // [HID][N]
    float* T1part = ws + 2048 + 2 * HID * N_SAMP; // [2][N][N] = 8 MB

    gemm_xy     <<<dim3(N_SAMP / 4),  dim3(256), 0, stream>>>(x, y, W1, b1,
                                                              xpbT, ypT, T0s);
    pair_partial<<<dim3(16, 16, 2),   dim3(256), 0, stream>>>(ypT, xpbT, W2,
                                                              T1part);
    row_lse     <<<dim3(N_SAMP),      dim3(256), 0, stream>>>(T1part, S, T0s);
    finalize    <<<dim3(1),           dim3(256), 0, stream>>>(S, T0s, b2,
                                                              (float*)d_out);
}